// Round 7
// baseline (620.813 us; speedup 1.0000x reference)
//
#include <hip/hip_runtime.h>
#include <hip/hip_bf16.h>

#define CB 64      // B == C == 64
#define HH 128
#define WW 128
#define KK 4
#define EPSV 1e-5f
#define HWSZ (HH*WW)

using f32x4  = __attribute__((ext_vector_type(4))) float;
using short8 = __attribute__((ext_vector_type(8))) short;

// ---- workspace layout ----
static constexpr size_t WS_POOLED = 0;          // [64][128]
static constexpr size_t WS_HID    = 8192;       // [64][64]
static constexpr size_t WS_KERN   = 12288;      // [64][2304] (dead after k_wk; bf16 weights reuse bytes)
static constexpr size_t WS_SSQ    = 159744;     // [64][4]
static constexpr size_t WS_WK     = 160000;     // [64][576]
static constexpr size_t WS_EFFW   = 196864;     // [64][576]
static constexpr size_t WS_FUW2   = 233728;     // [64][64]
static constexpr size_t WS_FDINV  = 237824;     // [64]
static constexpr size_t WS_FDBETA = 237888;     // [64]
static constexpr size_t WS_FUINV  = 237952;     // [64]
static constexpr size_t WS_FUBETA = 238016;     // [64]
// byte offsets inside dead WS_KERN byte range (49152..638976):
static constexpr size_t WT3_BYTE = 49152;              // bf16 [9][64][64]
static constexpr size_t WFD_BYTE = 49152 + 73728;      // bf16 [9][64][64]
static constexpr size_t W1_BYTE  = 49152 + 147456;     // bf16 [64][64]
// big buffers:
static constexpr size_t WS_PART_BYTE   = 4u << 20;     // f32 [64][128][128] partial row sums
static constexpr size_t WS_DEPTHT_BYTE = 8u << 20;     // bf16 [64][130][130][64] zero-padded
static constexpr size_t WS_RGBT_BYTE   = 140u << 20;   // bf16 [64][130][130][64] zero-padded

// ---------------- small kernels (verified rounds 1-6) ----------------

__global__ void k_consts(const float* __restrict__ fd_scale, const float* __restrict__ fd_bias,
                         const float* __restrict__ fd_mean, const float* __restrict__ fd_var,
                         const float* __restrict__ fd_b,
                         const float* __restrict__ fu_scale, const float* __restrict__ fu_bias,
                         const float* __restrict__ fu_mean, const float* __restrict__ fu_var,
                         const float* __restrict__ fu_b,
                         float* __restrict__ ws) {
    int c = threadIdx.x;
    if (c < CB) {
        float fdi = fd_scale[c] / sqrtf(fd_var[c] + EPSV);
        ws[WS_FDINV + c]  = fdi;
        ws[WS_FDBETA + c] = (fd_b[c] - fd_mean[c]) * fdi + fd_bias[c];
        float fui = fu_scale[c] / sqrtf(fu_var[c] + EPSV);
        ws[WS_FUINV + c]  = fui;
        ws[WS_FUBETA + c] = (fu_b[c] - fu_mean[c]) * fui + fu_bias[c];
    }
}

__device__ __forceinline__ unsigned int pack_bf16(float a, float b) {
    __hip_bfloat16 ha = __float2bfloat16(a), hb = __float2bfloat16(b);
    return (unsigned int)*(unsigned short*)&ha | ((unsigned int)*(unsigned short*)&hb << 16);
}

// NCHW f32 -> padded NHWC bf16 transpose (rgb & depth) + pool partials.
// Restructured: all 4 phases staged to LDS, ONE barrier, then all stores.
__global__ __launch_bounds__(256) void k_nhwc(const float* __restrict__ rgb,
                                              const float* __restrict__ depth,
                                              unsigned int* __restrict__ rgbT,
                                              unsigned int* __restrict__ depthT,
                                              float* __restrict__ part) {
    int yp = blockIdx.x;   // 0..129 padded row
    int b  = blockIdx.y;
    int t  = threadIdx.x;
    unsigned int* dstR = rgbT   + ((size_t)b * 130 + yp) * 130 * 32;
    unsigned int* dstD = depthT + ((size_t)b * 130 + yp) * 130 * 32;

    if (yp == 0 || yp == 129) {
        for (int i = t; i < 130 * 32; i += 256) { dstR[i] = 0u; dstD[i] = 0u; }
        return;
    }
    int y = yp - 1;
    if (t < 128) {
        int tensor = t >> 6, side = (t >> 5) & 1, j = t & 31;
        unsigned int* d = tensor ? dstD : dstR;
        d[(side ? 129 : 0) * 32 + j] = 0u;
    }

    __shared__ unsigned int lds_t[4 * 2176];   // per-phase [128 px][17] (pad)
    __shared__ float poolacc[4][128];
    int x = t & 127, cpl = t >> 7, w = t >> 6, lane = t & 63;

    #pragma unroll
    for (int ph = 0; ph < 4; ++ph) {
        const float* src = (ph >> 1) ? depth : rgb;
        int chbase = (ph & 1) * 32;
        #pragma unroll
        for (int i = 0; i < 8; ++i) {
            int cpair = i * 2 + cpl;                  // 0..15
            int c = chbase + cpair * 2;
            float v0 = src[(((size_t)b * CB + c    ) * HH + y) * WW + x];
            float v1 = src[(((size_t)b * CB + c + 1) * HH + y) * WW + x];
            lds_t[ph * 2176 + x * 17 + cpair] = pack_bf16(v0, v1);
            float s0 = v0, s1 = v1;
            #pragma unroll
            for (int off = 32; off; off >>= 1) {
                s0 += __shfl_down(s0, off, 64);
                s1 += __shfl_down(s1, off, 64);
            }
            if (lane == 0) {
                int cc = (ph >> 1) * 64 + c;
                poolacc[w][cc] = s0;
                poolacc[w][cc + 1] = s1;
            }
        }
    }
    __syncthreads();

    {
        int p = t >> 1, h = t & 1;
        #pragma unroll
        for (int ph = 0; ph < 4; ++ph) {
            unsigned int vv[8];
            #pragma unroll
            for (int j = 0; j < 8; ++j) vv[j] = lds_t[ph * 2176 + p * 17 + h * 8 + j];
            unsigned int* dst = (ph >> 1) ? dstD : dstR;
            unsigned int* dp = dst + (p + 1) * 32 + (ph & 1) * 16 + h * 8;
            uint4 q0 = {vv[0], vv[1], vv[2], vv[3]};
            uint4 q1 = {vv[4], vv[5], vv[6], vv[7]};
            *(uint4*)dp = q0;
            *(uint4*)(dp + 4) = q1;
        }
    }
    if (t < 128) {
        int w0 = 2 * ((t >> 1) & 1);
        part[((size_t)b * 128 + y) * 128 + t] = poolacc[w0][t] + poolacc[w0 + 1][t];
    }
}

__global__ __launch_bounds__(256) void k_pool2(const float* __restrict__ part,
                                               float* __restrict__ ws) {
    int b = blockIdx.x, t = threadIdx.x, cc = t & 127, q = t >> 7;
    float s = 0.f;
    for (int y = q * 64; y < q * 64 + 64; ++y)
        s += part[((size_t)b * 128 + y) * 128 + cc];
    __shared__ float red[2][128];
    red[q][cc] = s;
    __syncthreads();
    if (t < 128)
        ws[WS_POOLED + b * 128 + t] = (red[0][t] + red[1][t]) * (1.f / 16384.f);
}

__global__ void k_hid(const float* __restrict__ w1, const float* __restrict__ b1,
                      float* __restrict__ ws) {
    __shared__ float p[128];
    int b = blockIdx.x, j = threadIdx.x;
    p[j] = ws[WS_POOLED + b * 128 + j];
    __syncthreads();
    if (j < CB) {
        float s = b1[j];
        const float* wr = w1 + j * 128;
        #pragma unroll 8
        for (int i = 0; i < 128; ++i) s += p[i] * wr[i];
        ws[WS_HID + b * CB + j] = fmaxf(s, 0.f);
    }
}

__global__ __launch_bounds__(256) void k_kern(const float* __restrict__ w2, const float* __restrict__ b2,
                                              float* __restrict__ ws) {
    __shared__ float h[CB];
    int b = blockIdx.x, t = threadIdx.x;
    if (t < CB) h[t] = ws[WS_HID + b * CB + t];
    __syncthreads();
    float local = 0.f;
    #pragma unroll
    for (int r9 = 0; r9 < 9; ++r9) {
        int r = t * 9 + r9;
        float s = b2[r];
        const float* wr = w2 + r * CB;
        #pragma unroll 8
        for (int m = 0; m < CB; ++m) s += h[m] * wr[m];
        ws[WS_KERN + b * 2304 + r] = s;
        local += s * s;
    }
    #pragma unroll
    for (int off = 32; off; off >>= 1) local += __shfl_down(local, off, 64);
    if ((t & 63) == 0) ws[WS_SSQ + b * KK + (t >> 6)] = local;
}

__global__ __launch_bounds__(256) void k_wk(float* __restrict__ ws) {
    __shared__ float attn[KK];
    int b = blockIdx.x, t = threadIdx.x;
    if (t == 0) {
        float n[KK], m = -1e30f;
        #pragma unroll
        for (int k = 0; k < KK; ++k) { n[k] = sqrtf(ws[WS_SSQ + b * KK + k]); m = fmaxf(m, n[k]); }
        float e[KK], den = 0.f;
        #pragma unroll
        for (int k = 0; k < KK; ++k) { e[k] = expf(n[k] - m); den += e[k]; }
        float inv = 1.f / den;
        #pragma unroll
        for (int k = 0; k < KK; ++k) attn[k] = e[k] * inv;
    }
    __syncthreads();
    const float* kb = ws + WS_KERN + b * 2304;
    float a0 = attn[0], a1 = attn[1], a2 = attn[2], a3 = attn[3];
    for (int idx = t; idx < 576; idx += 256) {
        float s = a0 * kb[idx] + a1 * kb[576 + idx] + a2 * kb[1152 + idx] + a3 * kb[1728 + idx];
        ws[WS_WK + b * 576 + idx] = s;
    }
}

__global__ __launch_bounds__(256) void k_effw(const float* __restrict__ fu_w, float* __restrict__ ws) {
    int o = blockIdx.x, t = threadIdx.x;
    __shared__ float fw[CB];
    float fi = ws[WS_FUINV + o];
    if (t < CB) {
        fw[t] = fu_w[o * 128 + t] * fi;
        ws[WS_FUW2 + o * CB + t] = fu_w[o * 128 + CB + t] * fi;
    }
    __syncthreads();
    for (int idx = t; idx < 576; idx += 256) {
        float s = 0.f;
        #pragma unroll 8
        for (int c = 0; c < CB; ++c) s += fw[c] * ws[WS_WK + c * 576 + idx];
        ws[WS_EFFW + o * 576 + idx] = s;
    }
}

__global__ void k_prepw(const float* __restrict__ fd_w, float* __restrict__ ws) {
    int e = blockIdx.x * 256 + threadIdx.x;
    unsigned short* wt3 = (unsigned short*)((char*)ws + WT3_BYTE);
    unsigned short* wfd = (unsigned short*)((char*)ws + WFD_BYTE);
    unsigned short* w1o = (unsigned short*)((char*)ws + W1_BYTE);
    if (e < 36864) {
        int tap = e >> 12, rem = e & 4095, o = rem >> 6, ci = rem & 63;
        __hip_bfloat16 h = __float2bfloat16(ws[WS_EFFW + o * 576 + ci * 9 + tap]);
        wt3[e] = *(unsigned short*)&h;
    } else if (e < 73728) {
        int e2 = e - 36864;
        int tap = e2 >> 12, rem = e2 & 4095, o = rem >> 6, ci = rem & 63;
        __hip_bfloat16 h = __float2bfloat16(fd_w[(o * 64 + ci) * 9 + tap] * ws[WS_FDINV + o]);
        wfd[e2] = *(unsigned short*)&h;
    } else if (e < 77824) {
        int e3 = e - 73728;
        __hip_bfloat16 h = __float2bfloat16(ws[WS_FUW2 + e3]);
        w1o[e3] = *(unsigned short*)&h;
    }
}

// ---------------- fused conv kernel (weight-stationary) ----------------
// Tile 32x8 px. Input LDS: [10 rows][34 x][8 chunks of 8 bf16] = 43520 B,
// linear dest, XOR swizzle (cs ^ (x&7)) on global source + ds_read side.
// Wave w owns output channels [16w, 16w+16) for ALL 256 tile pixels;
// the 18 weight A-fragments/conv live in registers for the whole conv.

__device__ __forceinline__ void gload_lds16(const void* g, void* l) {
    __builtin_amdgcn_global_load_lds((const __attribute__((address_space(1))) unsigned int*)g,
                                     (__attribute__((address_space(3))) unsigned int*)l, 16, 0, 0);
}

__device__ __forceinline__ void stage_async(const unsigned short* __restrict__ T, int b,
                                            int y0p, int x0p, int t, char* tile) {
    const char* base = (const char*)(T + (((size_t)b * 130 + y0p) * 130 + x0p) * 64);
    #pragma unroll
    for (int it = 0; it < 10; ++it) {
        int n = it * 256 + t;
        int row = n / 272, rem = n - row * 272;
        int xx = rem >> 3, cs = rem & 7;
        gload_lds16(base + (size_t)row * 16640 + xx * 128 + ((cs ^ (xx & 7)) << 4),
                    tile + n * 16);
    }
    if (t < 160) {
        int n = 2560 + t;
        int row = n / 272, rem = n - row * 272;
        int xx = rem >> 3, cs = rem & 7;
        gload_lds16(base + (size_t)row * 16640 + xx * 128 + ((cs ^ (xx & 7)) << 4),
                    tile + n * 16);
    }
}

// load the 18 A-fragments for one conv phase (wave's 16 out-channels)
__device__ __forceinline__ void load_wfrag(short8 (&wa)[18], const unsigned short* __restrict__ W,
                                           int w, int lx, int lq) {
    #pragma unroll
    for (int tap = 0; tap < 9; ++tap)
        #pragma unroll
        for (int cb = 0; cb < 2; ++cb)
            wa[tap * 2 + cb] = *(const short8*)(W + (tap * 64 + w * 16 + lx) * 64 + cb * 32 + lq * 8);
}

// conv3x3 with register-resident weights; B-frags via base+imm ds_reads.
__device__ __forceinline__ void conv3x3w(f32x4 (&acc)[16], const short8 (&wa)[18],
                                         const char* tile, int lx, int lq) {
    #pragma unroll
    for (int dj = 0; dj < 3; ++dj) {
        #pragma unroll
        for (int cb = 0; cb < 2; ++cb) {
            const char* base = tile + (lx + dj) * 128 + (((cb * 4 + lq) ^ ((lx + dj) & 7)) << 4);
            #pragma unroll
            for (int di = 0; di < 3; ++di) {
                short8 aw = wa[(di * 3 + dj) * 2 + cb];
                __builtin_amdgcn_s_setprio(1);
                #pragma unroll
                for (int nt = 0; nt < 16; ++nt) {
                    short8 bf = *(const short8*)(base + (nt >> 1) * 4352 + di * 4352 + (nt & 1) * 2048);
                    acc[nt] = __builtin_amdgcn_mfma_f32_16x16x32_bf16(aw, bf, acc[nt], 0, 0, 0);
                }
                __builtin_amdgcn_s_setprio(0);
            }
        }
    }
}

__global__ __launch_bounds__(256, 3) void k_fused(const unsigned short* __restrict__ rgbT,
                                                  const unsigned short* __restrict__ depthT,
                                                  const float* __restrict__ ws,
                                                  float* __restrict__ out) {
    __shared__ __align__(16) char tile[43520];
    // bijective XCD swizzle (4096 = 8*512): XCD k owns 8 complete batches ->
    // x-neighbors (write-span completion) and y-neighbors (halo) co-XCD.
    int id = blockIdx.x;
    int swz = (id & 7) * 512 + (id >> 3);
    int bx = swz & 3, by = (swz >> 2) & 15, b = swz >> 6;
    int x0 = bx * 32, y0 = by * 8;
    int t = threadIdx.x, lane = t & 63, w = t >> 6;
    int lx = lane & 15, lq = lane >> 4;

    const unsigned short* wfd = (const unsigned short*)((const char*)ws + WFD_BYTE);
    const unsigned short* wt3 = (const unsigned short*)((const char*)ws + WT3_BYTE);
    const unsigned short* w1o = (const unsigned short*)((const char*)ws + W1_BYTE);

    // ---- issue depth tile loads (async into LDS); weights load beneath ----
    stage_async(depthT, b, y0, x0, t, tile);

    short8 wa[18];
    load_wfrag(wa, wfd, w, lx, lq);

    f32x4 facc[16];
    {
        f32x4 bi;
        #pragma unroll
        for (int i = 0; i < 4; ++i) bi[i] = ws[WS_FDBETA + w * 16 + lq * 4 + i];
        #pragma unroll
        for (int nt = 0; nt < 16; ++nt) facc[nt] = bi;
    }
    __syncthreads();   // depth tile resident

    // ---- freq = relu(BN(conv3x3(depth))), wave's 16 channels x 256 px ----
    conv3x3w(facc, wa, tile, lx, lq);
    __syncthreads();   // depth-tile reads done; reuse tile[0..32768) as freq_lds

    // ---- write freq to LDS: [pixel][ch] bf16, 16B-slot XOR by (p&7) ----
    {
        unsigned int* fl = (unsigned int*)tile;
        #pragma unroll
        for (int nt = 0; nt < 16; ++nt) {
            int p = nt * 16 + lx;
            unsigned int u0 = pack_bf16(fmaxf(facc[nt][0], 0.f), fmaxf(facc[nt][1], 0.f));
            unsigned int u1 = pack_bf16(fmaxf(facc[nt][2], 0.f), fmaxf(facc[nt][3], 0.f));
            int slot = ((w * 2) + (lq >> 1)) ^ (p & 7);
            int dw = p * 32 + slot * 4 + (lq & 1) * 2;
            fl[dw] = u0;
            fl[dw + 1] = u1;
        }
    }
    __syncthreads();   // freq_lds visible

    // ---- acc init + 1x1 over freq (A = w1 frags in regs, B from freq_lds) ----
    f32x4 acc[16];
    {
        f32x4 bi;
        #pragma unroll
        for (int i = 0; i < 4; ++i) bi[i] = ws[WS_FUBETA + w * 16 + lq * 4 + i];
        #pragma unroll
        for (int nt = 0; nt < 16; ++nt) acc[nt] = bi;
    }
    #pragma unroll
    for (int cb = 0; cb < 2; ++cb) {
        short8 aw = *(const short8*)(w1o + (w * 16 + lx) * 64 + cb * 32 + lq * 8);
        __builtin_amdgcn_s_setprio(1);
        #pragma unroll
        for (int nt = 0; nt < 16; ++nt) {
            int p = nt * 16 + lx;
            int slot = (cb * 4 + lq) ^ (p & 7);
            short8 bf = *(const short8*)(tile + p * 128 + slot * 16);
            acc[nt] = __builtin_amdgcn_mfma_f32_16x16x32_bf16(aw, bf, acc[nt], 0, 0, 0);
        }
        __builtin_amdgcn_s_setprio(0);
    }
    __syncthreads();   // freq_lds reads done

    // ---- issue rgb tile loads; wt3 frags load beneath ----
    stage_async(rgbT, b, y0, x0, t, tile);
    load_wfrag(wa, wt3, w, lx, lq);
    __syncthreads();   // rgb tile resident

    // ---- dynamic conv over rgb ----
    conv3x3w(acc, wa, tile, lx, lq);
    __syncthreads();   // tile reads done; reuse as transpose slab

    // ---- epilogue: per-wave LDS transpose -> full-128B-line stores ----
    float* slab = (float*)tile + w * 528;      // 16 ch x 33 floats
    int og = lane >> 5, xi = lane & 31;
    #pragma unroll
    for (int y = 0; y < 8; ++y) {
        #pragma unroll
        for (int xh = 0; xh < 2; ++xh) {
            int nt = y * 2 + xh;
            #pragma unroll
            for (int i = 0; i < 4; ++i)
                slab[(lq * 4 + i) * 33 + xh * 16 + lx] = fmaxf(acc[nt][i], 0.f);
        }
        size_t rowbase = (((size_t)(b * CB + w * 16)) * HH + (y0 + y)) * WW + x0;
        #pragma unroll
        for (int k = 0; k < 8; ++k) {
            int o = k * 2 + og;
            out[rowbase + (size_t)o * HWSZ + xi] = slab[o * 33 + xi];
        }
    }
}

// ---------------- launch ----------------

extern "C" void kernel_launch(void* const* d_in, const int* in_sizes, int n_in,
                              void* d_out, int out_size, void* d_ws, size_t ws_size,
                              hipStream_t stream) {
    const float* rgb      = (const float*)d_in[0];
    const float* depth    = (const float*)d_in[1];
    const float* w1       = (const float*)d_in[2];
    const float* b1       = (const float*)d_in[3];
    const float* w2       = (const float*)d_in[4];
    const float* b2       = (const float*)d_in[5];
    const float* fd_w     = (const float*)d_in[6];
    const float* fd_b     = (const float*)d_in[7];
    const float* fd_scale = (const float*)d_in[8];
    const float* fd_bias  = (const float*)d_in[9];
    const float* fd_mean  = (const float*)d_in[10];
    const float* fd_var   = (const float*)d_in[11];
    const float* fu_w     = (const float*)d_in[12];
    const float* fu_b     = (const float*)d_in[13];
    const float* fu_scale = (const float*)d_in[14];
    const float* fu_bias  = (const float*)d_in[15];
    const float* fu_mean  = (const float*)d_in[16];
    const float* fu_var   = (const float*)d_in[17];

    float* ws = (float*)d_ws;
    float* part = (float*)((char*)d_ws + WS_PART_BYTE);
    unsigned int* depthT = (unsigned int*)((char*)d_ws + WS_DEPTHT_BYTE);
    unsigned int* rgbT   = (unsigned int*)((char*)d_ws + WS_RGBT_BYTE);
    float* out = (float*)d_out;

    k_consts<<<1, 64, 0, stream>>>(fd_scale, fd_bias, fd_mean, fd_var, fd_b,
                                   fu_scale, fu_bias, fu_mean, fu_var, fu_b, ws);
    k_nhwc<<<dim3(130, 64), 256, 0, stream>>>(rgb, depth, rgbT, depthT, part);
    k_pool2<<<CB, 256, 0, stream>>>(part, ws);
    k_hid<<<CB, 128, 0, stream>>>(w1, b1, ws);
    k_kern<<<CB, 256, 0, stream>>>(w2, b2, ws);
    k_wk<<<CB, 256, 0, stream>>>(ws);
    k_effw<<<CB, 256, 0, stream>>>(fu_w, ws);
    k_prepw<<<304, 256, 0, stream>>>(fd_w, ws);

    k_fused<<<4096, 256, 0, stream>>>((const unsigned short*)rgbT,
                                      (const unsigned short*)depthT, ws, out);
}

// Round 8
// 541.309 us; speedup vs baseline: 1.1469x; 1.1469x over previous
//
#include <hip/hip_runtime.h>
#include <hip/hip_bf16.h>

#define CB 64      // B == C == 64
#define HH 128
#define WW 128
#define KK 4
#define EPSV 1e-5f
#define HWSZ (HH*WW)

using f32x4   = __attribute__((ext_vector_type(4))) float;
using f32x16  = __attribute__((ext_vector_type(16))) float;
using short8  = __attribute__((ext_vector_type(8))) short;

// ---- workspace layout ----
static constexpr size_t WS_POOLED = 0;          // [64][128]
static constexpr size_t WS_HID    = 8192;       // [64][64]
static constexpr size_t WS_KERN   = 12288;      // [64][2304] (dead after k_wk; bf16 weights reuse bytes)
static constexpr size_t WS_SSQ    = 159744;     // [64][4]
static constexpr size_t WS_WK     = 160000;     // [64][576]
static constexpr size_t WS_EFFW   = 196864;     // [64][576]
static constexpr size_t WS_FUW2   = 233728;     // [64][64]
static constexpr size_t WS_FDINV  = 237824;     // [64]
static constexpr size_t WS_FDBETA = 237888;     // [64]
static constexpr size_t WS_FUINV  = 237952;     // [64]
static constexpr size_t WS_FUBETA = 238016;     // [64]
// byte offsets inside dead WS_KERN byte range (49152..638976):
// NEW lane-coalesced weight layout: [tap][Kq][oh][lane 0..63][8 bf16]
static constexpr size_t WT3_BYTE = 49152;              // bf16 36864 = 73728 B
static constexpr size_t WFD_BYTE = 49152 + 73728;      // bf16 36864
static constexpr size_t W1_BYTE  = 49152 + 147456;     // bf16 [Kq][oh][lane][8] = 4096
// big buffers:
static constexpr size_t WS_PART_BYTE   = 4u << 20;     // f32 [64][128][128] partial row sums
static constexpr size_t WS_DEPTHT_BYTE = 8u << 20;     // bf16 [64][130][130][64] zero-padded
static constexpr size_t WS_RGBT_BYTE   = 140u << 20;   // bf16 [64][130][130][64] zero-padded

// ---------------- small kernels (verified rounds 1-6) ----------------

__global__ void k_consts(const float* __restrict__ fd_scale, const float* __restrict__ fd_bias,
                         const float* __restrict__ fd_mean, const float* __restrict__ fd_var,
                         const float* __restrict__ fd_b,
                         const float* __restrict__ fu_scale, const float* __restrict__ fu_bias,
                         const float* __restrict__ fu_mean, const float* __restrict__ fu_var,
                         const float* __restrict__ fu_b,
                         float* __restrict__ ws) {
    int c = threadIdx.x;
    if (c < CB) {
        float fdi = fd_scale[c] / sqrtf(fd_var[c] + EPSV);
        ws[WS_FDINV + c]  = fdi;
        ws[WS_FDBETA + c] = (fd_b[c] - fd_mean[c]) * fdi + fd_bias[c];
        float fui = fu_scale[c] / sqrtf(fu_var[c] + EPSV);
        ws[WS_FUINV + c]  = fui;
        ws[WS_FUBETA + c] = (fu_b[c] - fu_mean[c]) * fui + fu_bias[c];
    }
}

__device__ __forceinline__ unsigned int pack_bf16(float a, float b) {
    __hip_bfloat16 ha = __float2bfloat16(a), hb = __float2bfloat16(b);
    return (unsigned int)*(unsigned short*)&ha | ((unsigned int)*(unsigned short*)&hb << 16);
}

// NCHW f32 -> padded NHWC bf16 transpose + pool partials (round-2..6 version).
__global__ __launch_bounds__(256) void k_nhwc(const float* __restrict__ rgb,
                                              const float* __restrict__ depth,
                                              unsigned int* __restrict__ rgbT,
                                              unsigned int* __restrict__ depthT,
                                              float* __restrict__ part) {
    int yp = blockIdx.x;   // 0..129 padded row
    int b  = blockIdx.y;
    int t  = threadIdx.x;
    unsigned int* dstR = rgbT   + ((size_t)b * 130 + yp) * 130 * 32;
    unsigned int* dstD = depthT + ((size_t)b * 130 + yp) * 130 * 32;

    if (yp == 0 || yp == 129) {
        for (int i = t; i < 130 * 32; i += 256) { dstR[i] = 0u; dstD[i] = 0u; }
        return;
    }
    int y = yp - 1;
    if (t < 128) {
        int tensor = t >> 6, side = (t >> 5) & 1, j = t & 31;
        unsigned int* d = tensor ? dstD : dstR;
        d[(side ? 129 : 0) * 32 + j] = 0u;
    }

    __shared__ unsigned int lds_t[128 * 17];
    __shared__ float poolacc[4][128];
    int x = t & 127, cpl = t >> 7, w = t >> 6, lane = t & 63;

    #pragma unroll
    for (int ph = 0; ph < 4; ++ph) {
        const float* src = (ph >> 1) ? depth : rgb;
        int chbase = (ph & 1) * 32;
        #pragma unroll
        for (int i = 0; i < 8; ++i) {
            int cpair = i * 2 + cpl;
            int c = chbase + cpair * 2;
            float v0 = src[(((size_t)b * CB + c    ) * HH + y) * WW + x];
            float v1 = src[(((size_t)b * CB + c + 1) * HH + y) * WW + x];
            lds_t[x * 17 + cpair] = pack_bf16(v0, v1);
            float s0 = v0, s1 = v1;
            #pragma unroll
            for (int off = 32; off; off >>= 1) {
                s0 += __shfl_down(s0, off, 64);
                s1 += __shfl_down(s1, off, 64);
            }
            if (lane == 0) {
                int cc = (ph >> 1) * 64 + c;
                poolacc[w][cc] = s0;
                poolacc[w][cc + 1] = s1;
            }
        }
        __syncthreads();
        {
            int p = t >> 1, h = t & 1;
            unsigned int vv[8];
            #pragma unroll
            for (int j = 0; j < 8; ++j) vv[j] = lds_t[p * 17 + h * 8 + j];
            unsigned int* dst = (ph >> 1) ? dstD : dstR;
            unsigned int* dp = dst + (p + 1) * 32 + (chbase >> 1) + h * 8;
            uint4 q0 = {vv[0], vv[1], vv[2], vv[3]};
            uint4 q1 = {vv[4], vv[5], vv[6], vv[7]};
            *(uint4*)dp = q0;
            *(uint4*)(dp + 4) = q1;
        }
        __syncthreads();
    }
    if (t < 128) {
        int w0 = 2 * ((t >> 1) & 1);
        part[((size_t)b * 128 + y) * 128 + t] = poolacc[w0][t] + poolacc[w0 + 1][t];
    }
}

__global__ __launch_bounds__(256) void k_pool2(const float* __restrict__ part,
                                               float* __restrict__ ws) {
    int b = blockIdx.x, t = threadIdx.x, cc = t & 127, q = t >> 7;
    float s = 0.f;
    for (int y = q * 64; y < q * 64 + 64; ++y)
        s += part[((size_t)b * 128 + y) * 128 + cc];
    __shared__ float red[2][128];
    red[q][cc] = s;
    __syncthreads();
    if (t < 128)
        ws[WS_POOLED + b * 128 + t] = (red[0][t] + red[1][t]) * (1.f / 16384.f);
}

__global__ void k_hid(const float* __restrict__ w1, const float* __restrict__ b1,
                      float* __restrict__ ws) {
    __shared__ float p[128];
    int b = blockIdx.x, j = threadIdx.x;
    p[j] = ws[WS_POOLED + b * 128 + j];
    __syncthreads();
    if (j < CB) {
        float s = b1[j];
        const float* wr = w1 + j * 128;
        #pragma unroll 8
        for (int i = 0; i < 128; ++i) s += p[i] * wr[i];
        ws[WS_HID + b * CB + j] = fmaxf(s, 0.f);
    }
}

__global__ __launch_bounds__(256) void k_kern(const float* __restrict__ w2, const float* __restrict__ b2,
                                              float* __restrict__ ws) {
    __shared__ float h[CB];
    int b = blockIdx.x, t = threadIdx.x;
    if (t < CB) h[t] = ws[WS_HID + b * CB + t];
    __syncthreads();
    float local = 0.f;
    #pragma unroll
    for (int r9 = 0; r9 < 9; ++r9) {
        int r = t * 9 + r9;
        float s = b2[r];
        const float* wr = w2 + r * CB;
        #pragma unroll 8
        for (int m = 0; m < CB; ++m) s += h[m] * wr[m];
        ws[WS_KERN + b * 2304 + r] = s;
        local += s * s;
    }
    #pragma unroll
    for (int off = 32; off; off >>= 1) local += __shfl_down(local, off, 64);
    if ((t & 63) == 0) ws[WS_SSQ + b * KK + (t >> 6)] = local;
}

__global__ __launch_bounds__(256) void k_wk(float* __restrict__ ws) {
    __shared__ float attn[KK];
    int b = blockIdx.x, t = threadIdx.x;
    if (t == 0) {
        float n[KK], m = -1e30f;
        #pragma unroll
        for (int k = 0; k < KK; ++k) { n[k] = sqrtf(ws[WS_SSQ + b * KK + k]); m = fmaxf(m, n[k]); }
        float e[KK], den = 0.f;
        #pragma unroll
        for (int k = 0; k < KK; ++k) { e[k] = expf(n[k] - m); den += e[k]; }
        float inv = 1.f / den;
        #pragma unroll
        for (int k = 0; k < KK; ++k) attn[k] = e[k] * inv;
    }
    __syncthreads();
    const float* kb = ws + WS_KERN + b * 2304;
    float a0 = attn[0], a1 = attn[1], a2 = attn[2], a3 = attn[3];
    for (int idx = t; idx < 576; idx += 256) {
        float s = a0 * kb[idx] + a1 * kb[576 + idx] + a2 * kb[1152 + idx] + a3 * kb[1728 + idx];
        ws[WS_WK + b * 576 + idx] = s;
    }
}

__global__ __launch_bounds__(256) void k_effw(const float* __restrict__ fu_w, float* __restrict__ ws) {
    int o = blockIdx.x, t = threadIdx.x;
    __shared__ float fw[CB];
    float fi = ws[WS_FUINV + o];
    if (t < CB) {
        fw[t] = fu_w[o * 128 + t] * fi;
        ws[WS_FUW2 + o * CB + t] = fu_w[o * 128 + CB + t] * fi;
    }
    __syncthreads();
    for (int idx = t; idx < 576; idx += 256) {
        float s = 0.f;
        #pragma unroll 8
        for (int c = 0; c < CB; ++c) s += fw[c] * ws[WS_WK + c * 576 + idx];
        ws[WS_EFFW + o * 576 + idx] = s;
    }
}

// lane-coalesced A-frag layouts for mfma_32x32x16:
//   wt[(((tap*4+Kq)*2+oh)*64 + lane)*8 + j] = W[och = oh*32+(lane&31)][cin = Kq*16+(lane>>5)*8+j]
__global__ void k_prepw(const float* __restrict__ fd_w, float* __restrict__ ws) {
    int e = blockIdx.x * 256 + threadIdx.x;
    unsigned short* wt3 = (unsigned short*)((char*)ws + WT3_BYTE);
    unsigned short* wfd = (unsigned short*)((char*)ws + WFD_BYTE);
    unsigned short* w1o = (unsigned short*)((char*)ws + W1_BYTE);
    if (e < 73728) {
        int set = (e >= 36864) ? 1 : 0;
        int e2 = set ? e - 36864 : e;
        int j = e2 & 7, l = (e2 >> 3) & 63, oh = (e2 >> 9) & 1, Kq = (e2 >> 10) & 3, tap = e2 >> 12;
        int och = oh * 32 + (l & 31);
        int cin = Kq * 16 + (l >> 5) * 8 + j;
        float v = set ? fd_w[(och * 64 + cin) * 9 + tap] * ws[WS_FDINV + och]
                      : ws[WS_EFFW + och * 576 + cin * 9 + tap];
        __hip_bfloat16 h = __float2bfloat16(v);
        (set ? wfd : wt3)[e2] = *(unsigned short*)&h;
    } else if (e < 77824) {
        int e3 = e - 73728;
        int j = e3 & 7, l = (e3 >> 3) & 63, oh = (e3 >> 9) & 1, Kq = e3 >> 10;
        int och = oh * 32 + (l & 31);
        int cin = Kq * 16 + (l >> 5) * 8 + j;
        __hip_bfloat16 h = __float2bfloat16(ws[WS_FUW2 + och * CB + cin]);
        w1o[e3] = *(unsigned short*)&h;
    }
}

// ---------------- fused conv kernel (32x32x16, all-channel waves) ----------------
// Tile 32x8 px. Input LDS: [10 rows][34 x][8 chunks of 8 bf16] = 43520 B,
// linear dest, XOR swizzle (cs ^ (xx&7)) on global source + ds_read side.
// Wave w owns ALL 64 out-channels for rows {2w, 2w+1} (64 px). Each B-frag
// ds_read feeds TWO 32x32x16 MFMAs (both channel halves).

__device__ __forceinline__ void gload_lds16(const void* g, void* l) {
    __builtin_amdgcn_global_load_lds((const __attribute__((address_space(1))) unsigned int*)g,
                                     (__attribute__((address_space(3))) unsigned int*)l, 16, 0, 0);
}

__device__ __forceinline__ void stage_async(const unsigned short* __restrict__ T, int b,
                                            int y0p, int x0p, int t, char* tile) {
    const char* base = (const char*)(T + (((size_t)b * 130 + y0p) * 130 + x0p) * 64);
    #pragma unroll
    for (int it = 0; it < 10; ++it) {
        int n = it * 256 + t;
        int row = n / 272, rem = n - row * 272;
        int xx = rem >> 3, cs = rem & 7;
        gload_lds16(base + (size_t)row * 16640 + xx * 128 + ((cs ^ (xx & 7)) << 4),
                    tile + n * 16);
    }
    if (t < 160) {
        int n = 2560 + t;
        int row = n / 272, rem = n - row * 272;
        int xx = rem >> 3, cs = rem & 7;
        gload_lds16(base + (size_t)row * 16640 + xx * 128 + ((cs ^ (xx & 7)) << 4),
                    tile + n * 16);
    }
}

// conv3x3: per tap load 8 coalesced A-frags (L2), 2 pxg x 4 Kq B-frag reads,
// each B-frag -> 2 MFMAs.
__device__ __forceinline__ void conv3x3w2(f32x16 (&acc)[2][2], const unsigned short* __restrict__ Wt,
                                          const char* tile, int w, int lane) {
    int px = lane & 31, hi = lane >> 5;
    #pragma unroll
    for (int tap = 0; tap < 9; ++tap) {
        const int di = tap / 3, dj = tap % 3;
        short8 wa[2][4];
        #pragma unroll
        for (int Kq = 0; Kq < 4; ++Kq)
            #pragma unroll
            for (int oh = 0; oh < 2; ++oh)
                wa[oh][Kq] = *(const short8*)(Wt + ((((tap * 4 + Kq) * 2 + oh) * 64 + lane) << 3));
        const int xx = px + dj;
        #pragma unroll
        for (int pxg = 0; pxg < 2; ++pxg) {
            const char* base = tile + (w * 2 + pxg + di) * 4352 + xx * 128;
            #pragma unroll
            for (int Kq = 0; Kq < 4; ++Kq) {
                short8 bf = *(const short8*)(base + (((Kq * 2 + hi) ^ (xx & 7)) << 4));
                __builtin_amdgcn_s_setprio(1);
                acc[0][pxg] = __builtin_amdgcn_mfma_f32_32x32x16_bf16(wa[0][Kq], bf, acc[0][pxg], 0, 0, 0);
                acc[1][pxg] = __builtin_amdgcn_mfma_f32_32x32x16_bf16(wa[1][Kq], bf, acc[1][pxg], 0, 0, 0);
                __builtin_amdgcn_s_setprio(0);
            }
        }
    }
}

__global__ __launch_bounds__(256, 3) void k_fused(const unsigned short* __restrict__ rgbT,
                                                  const unsigned short* __restrict__ depthT,
                                                  const float* __restrict__ ws,
                                                  float* __restrict__ out) {
    __shared__ __align__(16) char tile[43520];
    int b = blockIdx.z;
    int x0 = blockIdx.x * 32, y0 = blockIdx.y * 8;
    int t = threadIdx.x, lane = t & 63, w = t >> 6;
    int px = lane & 31, hi = lane >> 5;

    const unsigned short* wfd = (const unsigned short*)((const char*)ws + WFD_BYTE);
    const unsigned short* wt3 = (const unsigned short*)((const char*)ws + WT3_BYTE);
    const unsigned short* w1o = (const unsigned short*)((const char*)ws + W1_BYTE);

    // ---- issue depth tile loads (async into LDS) ----
    stage_async(depthT, b, y0, x0, t, tile);

    // facc init = fd beta (C-layout: och = oh*32 + (r&3) + 8*(r>>2) + 4*hi)
    f32x16 facc[2][2];
    #pragma unroll
    for (int oh = 0; oh < 2; ++oh) {
        f32x16 bi;
        #pragma unroll
        for (int r = 0; r < 16; ++r)
            bi[r] = ws[WS_FDBETA + oh * 32 + (r & 3) + 8 * (r >> 2) + 4 * hi];
        facc[oh][0] = bi;
        facc[oh][1] = bi;
    }
    __syncthreads();   // depth tile resident

    conv3x3w2(facc, wfd, tile, w, lane);
    __syncthreads();   // depth-tile reads done; reuse tile[0..32768) as freq_lds

    // ---- freq -> LDS [px][ch] bf16, chunk-slot XOR by (px&7), ReLU ----
    {
        unsigned int* fl = (unsigned int*)tile;
        #pragma unroll
        for (int oh = 0; oh < 2; ++oh)
            #pragma unroll
            for (int pxg = 0; pxg < 2; ++pxg) {
                int p = (w * 2 + pxg) * 32 + px;
                #pragma unroll
                for (int q = 0; q < 4; ++q) {
                    unsigned int u0 = pack_bf16(fmaxf(facc[oh][pxg][q * 4 + 0], 0.f),
                                                fmaxf(facc[oh][pxg][q * 4 + 1], 0.f));
                    unsigned int u1 = pack_bf16(fmaxf(facc[oh][pxg][q * 4 + 2], 0.f),
                                                fmaxf(facc[oh][pxg][q * 4 + 3], 0.f));
                    int slot = (q + oh * 4) ^ (p & 7);
                    int dw = p * 32 + slot * 4 + hi * 2;
                    fl[dw] = u0;
                    fl[dw + 1] = u1;
                }
            }
    }
    __syncthreads();   // freq_lds visible

    // ---- acc init + 1x1 over freq ----
    f32x16 acc[2][2];
    #pragma unroll
    for (int oh = 0; oh < 2; ++oh) {
        f32x16 bi;
        #pragma unroll
        for (int r = 0; r < 16; ++r)
            bi[r] = ws[WS_FUBETA + oh * 32 + (r & 3) + 8 * (r >> 2) + 4 * hi];
        acc[oh][0] = bi;
        acc[oh][1] = bi;
    }
    #pragma unroll
    for (int Kq = 0; Kq < 4; ++Kq) {
        short8 w1a[2];
        #pragma unroll
        for (int oh = 0; oh < 2; ++oh)
            w1a[oh] = *(const short8*)(w1o + (((Kq * 2 + oh) * 64 + lane) << 3));
        #pragma unroll
        for (int pxg = 0; pxg < 2; ++pxg) {
            int p = (w * 2 + pxg) * 32 + px;
            short8 bf = *(const short8*)(tile + p * 128 + (((Kq * 2 + hi) ^ (p & 7)) << 4));
            __builtin_amdgcn_s_setprio(1);
            acc[0][pxg] = __builtin_amdgcn_mfma_f32_32x32x16_bf16(w1a[0], bf, acc[0][pxg], 0, 0, 0);
            acc[1][pxg] = __builtin_amdgcn_mfma_f32_32x32x16_bf16(w1a[1], bf, acc[1][pxg], 0, 0, 0);
            __builtin_amdgcn_s_setprio(0);
        }
    }
    __syncthreads();   // freq_lds reads done

    // ---- issue rgb tile loads ----
    stage_async(rgbT, b, y0, x0, t, tile);
    __syncthreads();   // rgb tile resident

    conv3x3w2(acc, wt3, tile, w, lane);
    __syncthreads();   // tile reads done; reuse as transpose slab

    // ---- epilogue: per-wave 64x33 slab transpose -> full-128B-line stores ----
    float* slab = (float*)(tile + w * 8704);   // 64*33*4 = 8448 B per wave
    #pragma unroll
    for (int pxg = 0; pxg < 2; ++pxg) {
        #pragma unroll
        for (int oh = 0; oh < 2; ++oh)
            #pragma unroll
            for (int q = 0; q < 4; ++q)
                #pragma unroll
                for (int i = 0; i < 4; ++i)
                    slab[(oh * 32 + q * 8 + hi * 4 + i) * 33 + px] =
                        fmaxf(acc[oh][pxg][q * 4 + i], 0.f);
        int y = y0 + w * 2 + pxg;
        #pragma unroll
        for (int c2 = 0; c2 < 32; ++c2) {
            int c = c2 * 2 + hi;
            out[(size_t)(b * CB + c) * HWSZ + (size_t)y * WW + x0 + px] = slab[c * 33 + px];
        }
    }
}

// ---------------- launch ----------------

extern "C" void kernel_launch(void* const* d_in, const int* in_sizes, int n_in,
                              void* d_out, int out_size, void* d_ws, size_t ws_size,
                              hipStream_t stream) {
    const float* rgb      = (const float*)d_in[0];
    const float* depth    = (const float*)d_in[1];
    const float* w1       = (const float*)d_in[2];
    const float* b1       = (const float*)d_in[3];
    const float* w2       = (const float*)d_in[4];
    const float* b2       = (const float*)d_in[5];
    const float* fd_w     = (const float*)d_in[6];
    const float* fd_b     = (const float*)d_in[7];
    const float* fd_scale = (const float*)d_in[8];
    const float* fd_bias  = (const float*)d_in[9];
    const float* fd_mean  = (const float*)d_in[10];
    const float* fd_var   = (const float*)d_in[11];
    const float* fu_w     = (const float*)d_in[12];
    const float* fu_b     = (const float*)d_in[13];
    const float* fu_scale = (const float*)d_in[14];
    const float* fu_bias  = (const float*)d_in[15];
    const float* fu_mean  = (const float*)d_in[16];
    const float* fu_var   = (const float*)d_in[17];

    float* ws = (float*)d_ws;
    float* part = (float*)((char*)d_ws + WS_PART_BYTE);
    unsigned int* depthT = (unsigned int*)((char*)d_ws + WS_DEPTHT_BYTE);
    unsigned int* rgbT   = (unsigned int*)((char*)d_ws + WS_RGBT_BYTE);
    float* out = (float*)d_out;

    k_consts<<<1, 64, 0, stream>>>(fd_scale, fd_bias, fd_mean, fd_var, fd_b,
                                   fu_scale, fu_bias, fu_mean, fu_var, fu_b, ws);
    k_nhwc<<<dim3(130, 64), 256, 0, stream>>>(rgb, depth, rgbT, depthT, part);
    k_pool2<<<CB, 256, 0, stream>>>(part, ws);
    k_hid<<<CB, 128, 0, stream>>>(w1, b1, ws);
    k_kern<<<CB, 256, 0, stream>>>(w2, b2, ws);
    k_wk<<<CB, 256, 0, stream>>>(ws);
    k_effw<<<CB, 256, 0, stream>>>(fu_w, ws);
    k_prepw<<<304, 256, 0, stream>>>(fd_w, ws);

    dim3 grid(WW / 32, HH / 8, CB);
    k_fused<<<grid, 256, 0, stream>>>((const unsigned short*)rgbT,
                                      (const unsigned short*)depthT, ws, out);
}

// Round 9
// 473.183 us; speedup vs baseline: 1.3120x; 1.1440x over previous
//
#include <hip/hip_runtime.h>
#include <hip/hip_bf16.h>

#define CB 64      // B == C == 64
#define HH 128
#define WW 128
#define KK 4
#define EPSV 1e-5f
#define HWSZ (HH*WW)

using f32x4   = __attribute__((ext_vector_type(4))) float;
using f32x16  = __attribute__((ext_vector_type(16))) float;
using short8  = __attribute__((ext_vector_type(8))) short;

// ---- workspace layout ----
static constexpr size_t WS_POOLED = 0;          // [64][128]
static constexpr size_t WS_HID    = 8192;       // [64][64]
static constexpr size_t WS_KERN   = 12288;      // [64][2304] (dead after k_wk; bf16 weights reuse bytes)
static constexpr size_t WS_SSQ    = 159744;     // [64][4]
static constexpr size_t WS_WK     = 160000;     // [64][576]
static constexpr size_t WS_EFFW   = 196864;     // [64][576]
static constexpr size_t WS_FUW2   = 233728;     // [64][64]
static constexpr size_t WS_FDINV  = 237824;     // [64]
static constexpr size_t WS_FDBETA = 237888;     // [64]
static constexpr size_t WS_FUINV  = 237952;     // [64]
static constexpr size_t WS_FUBETA = 238016;     // [64]
// byte offsets inside dead WS_KERN byte range (49152..638976):
// lane-coalesced weight layout: [tap][Kq][oh][lane 0..63][8 bf16]
static constexpr size_t WT3_BYTE = 49152;              // bf16 36864 = 73728 B
static constexpr size_t WFD_BYTE = 49152 + 73728;      // bf16 36864
static constexpr size_t W1_BYTE  = 49152 + 147456;     // bf16 [Kq][oh][lane][8] = 4096
// big buffers:
static constexpr size_t WS_PART_BYTE   = 4u << 20;     // f32 [64][64 ypairs][128]
static constexpr size_t WS_DEPTHT_BYTE = 8u << 20;     // bf16 [64][130][130][64] zero-padded
static constexpr size_t WS_RGBT_BYTE   = 140u << 20;   // bf16 [64][130][130][64] zero-padded

// ---------------- small kernels ----------------

__global__ void k_consts(const float* __restrict__ fd_scale, const float* __restrict__ fd_bias,
                         const float* __restrict__ fd_mean, const float* __restrict__ fd_var,
                         const float* __restrict__ fd_b,
                         const float* __restrict__ fu_scale, const float* __restrict__ fu_bias,
                         const float* __restrict__ fu_mean, const float* __restrict__ fu_var,
                         const float* __restrict__ fu_b,
                         float* __restrict__ ws) {
    int c = threadIdx.x;
    if (c < CB) {
        float fdi = fd_scale[c] / sqrtf(fd_var[c] + EPSV);
        ws[WS_FDINV + c]  = fdi;
        ws[WS_FDBETA + c] = (fd_b[c] - fd_mean[c]) * fdi + fd_bias[c];
        float fui = fu_scale[c] / sqrtf(fu_var[c] + EPSV);
        ws[WS_FUINV + c]  = fui;
        ws[WS_FUBETA + c] = (fu_b[c] - fu_mean[c]) * fui + fu_bias[c];
    }
}

__device__ __forceinline__ unsigned int pack_bf16(float a, float b) {
    __hip_bfloat16 ha = __float2bfloat16(a), hb = __float2bfloat16(b);
    return (unsigned int)*(unsigned short*)&ha | ((unsigned int)*(unsigned short*)&hb << 16);
}

// NCHW f32 -> padded NHWC bf16 transpose + pool partials.
// 2-row batching: each block handles rows {2g, 2g+1} of one batch -> every
// NCHW read is a contiguous 1 KB chunk per channel (one full-wave dwordx4).
__global__ __launch_bounds__(256) void k_nhwc(const float* __restrict__ rgb,
                                              const float* __restrict__ depth,
                                              unsigned int* __restrict__ rgbT,
                                              unsigned int* __restrict__ depthT,
                                              float* __restrict__ part) {
    int g = blockIdx.x;    // 0..63 row-pairs; 64 = border-rows block
    int b = blockIdx.y;
    int t = threadIdx.x;

    if (g == 64) {         // zero padded rows yp=0,129 for both tensors
        unsigned int* dR0 = rgbT   + ((size_t)b * 130 + 0)   * 130 * 32;
        unsigned int* dR1 = rgbT   + ((size_t)b * 130 + 129) * 130 * 32;
        unsigned int* dD0 = depthT + ((size_t)b * 130 + 0)   * 130 * 32;
        unsigned int* dD1 = depthT + ((size_t)b * 130 + 129) * 130 * 32;
        for (int i = t; i < 130 * 32; i += 256) {
            dR0[i] = 0u; dR1[i] = 0u; dD0[i] = 0u; dD1[i] = 0u;
        }
        return;
    }
    int y0 = g * 2;
    {   // side borders x'=0,129 for padded rows y0+1, y0+2 (both tensors)
        int tensor = t >> 7, side = (t >> 6) & 1, row = (t >> 5) & 1, j = t & 31;
        unsigned int* d = tensor ? depthT : rgbT;
        d[(((size_t)b * 130 + (y0 + 1 + row)) * 130 + (side ? 129 : 0)) * 32 + j] = 0u;
    }

    __shared__ float staged[32][260];     // 32 ch x 256 px (2 rows), padded
    __shared__ float poolacc[128];
    int w = t >> 6, lane = t & 63;

    #pragma unroll
    for (int ph = 0; ph < 4; ++ph) {
        const float* src = (ph >> 1) ? depth : rgb;
        int chbase = (ph & 1) * 32;
        if (ph) __syncthreads();          // staged reuse barrier
        #pragma unroll
        for (int i = 0; i < 8; ++i) {
            int flat = i * 256 + t;
            int c = flat >> 6, f4 = flat & 63;    // wave-aligned: c = i*4 + w
            const float4* sp = (const float4*)(src + ((size_t)(b * CB + chbase + c)) * HWSZ
                                               + (size_t)y0 * WW);
            float4 v = sp[f4];
            *(float4*)&staged[c][f4 * 4] = v;
            float s = v.x + v.y + v.z + v.w;
            #pragma unroll
            for (int off = 32; off; off >>= 1) s += __shfl_down(s, off, 64);
            if (lane == 0) poolacc[(ph >> 1) * 64 + chbase + i * 4 + w] = s;
        }
        __syncthreads();
        {   // pack + write: thread t -> pixel (row = t>>7, x = t&127)
            int row = t >> 7, x = t & 127;
            unsigned int u[16];
            #pragma unroll
            for (int k = 0; k < 16; ++k)
                u[k] = pack_bf16(staged[2 * k][t], staged[2 * k + 1][t]);
            unsigned int* dst = (ph >> 1) ? depthT : rgbT;
            unsigned int* dp = dst + (((size_t)b * 130 + (y0 + 1 + row)) * 130 + 1 + x) * 32
                                   + (chbase >> 1);
            *(uint4*)dp        = *(uint4*)&u[0];
            *(uint4*)(dp + 4)  = *(uint4*)&u[4];
            *(uint4*)(dp + 8)  = *(uint4*)&u[8];
            *(uint4*)(dp + 12) = *(uint4*)&u[12];
        }
    }
    __syncthreads();
    if (t < 128)
        part[((size_t)b * 64 + g) * 128 + t] = poolacc[t];
}

__global__ __launch_bounds__(256) void k_pool2(const float* __restrict__ part,
                                               float* __restrict__ ws) {
    int b = blockIdx.x, t = threadIdx.x, cc = t & 127, q = t >> 7;
    float s = 0.f;
    for (int g = q * 32; g < q * 32 + 32; ++g)
        s += part[((size_t)b * 64 + g) * 128 + cc];
    __shared__ float red[2][128];
    red[q][cc] = s;
    __syncthreads();
    if (t < 128)
        ws[WS_POOLED + b * 128 + t] = (red[0][t] + red[1][t]) * (1.f / 16384.f);
}

__global__ void k_hid(const float* __restrict__ w1, const float* __restrict__ b1,
                      float* __restrict__ ws) {
    __shared__ float p[128];
    int b = blockIdx.x, j = threadIdx.x;
    p[j] = ws[WS_POOLED + b * 128 + j];
    __syncthreads();
    if (j < CB) {
        float s = b1[j];
        const float* wr = w1 + j * 128;
        #pragma unroll 8
        for (int i = 0; i < 128; ++i) s += p[i] * wr[i];
        ws[WS_HID + b * CB + j] = fmaxf(s, 0.f);
    }
}

__global__ __launch_bounds__(256) void k_kern(const float* __restrict__ w2, const float* __restrict__ b2,
                                              float* __restrict__ ws) {
    __shared__ float h[CB];
    int b = blockIdx.x, t = threadIdx.x;
    if (t < CB) h[t] = ws[WS_HID + b * CB + t];
    __syncthreads();
    float local = 0.f;
    #pragma unroll
    for (int r9 = 0; r9 < 9; ++r9) {
        int r = t * 9 + r9;
        float s = b2[r];
        const float* wr = w2 + r * CB;
        #pragma unroll 8
        for (int m = 0; m < CB; ++m) s += h[m] * wr[m];
        ws[WS_KERN + b * 2304 + r] = s;
        local += s * s;
    }
    #pragma unroll
    for (int off = 32; off; off >>= 1) local += __shfl_down(local, off, 64);
    if ((t & 63) == 0) ws[WS_SSQ + b * KK + (t >> 6)] = local;
}

__global__ __launch_bounds__(256) void k_wk(float* __restrict__ ws) {
    __shared__ float attn[KK];
    int b = blockIdx.x, t = threadIdx.x;
    if (t == 0) {
        float n[KK], m = -1e30f;
        #pragma unroll
        for (int k = 0; k < KK; ++k) { n[k] = sqrtf(ws[WS_SSQ + b * KK + k]); m = fmaxf(m, n[k]); }
        float e[KK], den = 0.f;
        #pragma unroll
        for (int k = 0; k < KK; ++k) { e[k] = expf(n[k] - m); den += e[k]; }
        float inv = 1.f / den;
        #pragma unroll
        for (int k = 0; k < KK; ++k) attn[k] = e[k] * inv;
    }
    __syncthreads();
    const float* kb = ws + WS_KERN + b * 2304;
    float a0 = attn[0], a1 = attn[1], a2 = attn[2], a3 = attn[3];
    for (int idx = t; idx < 576; idx += 256) {
        float s = a0 * kb[idx] + a1 * kb[576 + idx] + a2 * kb[1152 + idx] + a3 * kb[1728 + idx];
        ws[WS_WK + b * 576 + idx] = s;
    }
}

__global__ __launch_bounds__(256) void k_effw(const float* __restrict__ fu_w, float* __restrict__ ws) {
    int o = blockIdx.x, t = threadIdx.x;
    __shared__ float fw[CB];
    float fi = ws[WS_FUINV + o];
    if (t < CB) {
        fw[t] = fu_w[o * 128 + t] * fi;
        ws[WS_FUW2 + o * CB + t] = fu_w[o * 128 + CB + t] * fi;
    }
    __syncthreads();
    for (int idx = t; idx < 576; idx += 256) {
        float s = 0.f;
        #pragma unroll 8
        for (int c = 0; c < CB; ++c) s += fw[c] * ws[WS_WK + c * 576 + idx];
        ws[WS_EFFW + o * 576 + idx] = s;
    }
}

// lane-coalesced A-frag layouts for mfma_32x32x16:
//   wt[(((tap*4+Kq)*2+oh)*64 + lane)*8 + j] = W[och = oh*32+(lane&31)][cin = Kq*16+(lane>>5)*8+j]
__global__ void k_prepw(const float* __restrict__ fd_w, float* __restrict__ ws) {
    int e = blockIdx.x * 256 + threadIdx.x;
    unsigned short* wt3 = (unsigned short*)((char*)ws + WT3_BYTE);
    unsigned short* wfd = (unsigned short*)((char*)ws + WFD_BYTE);
    unsigned short* w1o = (unsigned short*)((char*)ws + W1_BYTE);
    if (e < 73728) {
        int set = (e >= 36864) ? 1 : 0;
        int e2 = set ? e - 36864 : e;
        int j = e2 & 7, l = (e2 >> 3) & 63, oh = (e2 >> 9) & 1, Kq = (e2 >> 10) & 3, tap = e2 >> 12;
        int och = oh * 32 + (l & 31);
        int cin = Kq * 16 + (l >> 5) * 8 + j;
        float v = set ? fd_w[(och * 64 + cin) * 9 + tap] * ws[WS_FDINV + och]
                      : ws[WS_EFFW + och * 576 + cin * 9 + tap];
        __hip_bfloat16 h = __float2bfloat16(v);
        (set ? wfd : wt3)[e2] = *(unsigned short*)&h;
    } else if (e < 77824) {
        int e3 = e - 73728;
        int j = e3 & 7, l = (e3 >> 3) & 63, oh = (e3 >> 9) & 1, Kq = e3 >> 10;
        int och = oh * 32 + (l & 31);
        int cin = Kq * 16 + (l >> 5) * 8 + j;
        __hip_bfloat16 h = __float2bfloat16(ws[WS_FUW2 + och * CB + cin]);
        w1o[e3] = *(unsigned short*)&h;
    }
}

// ---------------- fused conv kernel (32x32x16, all-channel waves) ----------------
// Tile 32x8 px. Input LDS: [10 rows][34 x][8 chunks of 8 bf16] = 43520 B,
// linear dest, XOR swizzle (cs ^ (xx&7)) on global source + ds_read side.
// Wave w owns ALL 64 out-channels for rows {2w, 2w+1} (64 px). Each B-frag
// ds_read feeds TWO 32x32x16 MFMAs.
// __launch_bounds__(256,2): 256-reg budget -> no scratch spill (round-8 WRITE
// excess = 41 KiB/block matched ~40 spilled regs x 256 thr).

__device__ __forceinline__ void gload_lds16(const void* g, void* l) {
    __builtin_amdgcn_global_load_lds((const __attribute__((address_space(1))) unsigned int*)g,
                                     (__attribute__((address_space(3))) unsigned int*)l, 16, 0, 0);
}

__device__ __forceinline__ void stage_async(const unsigned short* __restrict__ T, int b,
                                            int y0p, int x0p, int t, char* tile) {
    const char* base = (const char*)(T + (((size_t)b * 130 + y0p) * 130 + x0p) * 64);
    #pragma unroll
    for (int it = 0; it < 10; ++it) {
        int n = it * 256 + t;
        int row = n / 272, rem = n - row * 272;
        int xx = rem >> 3, cs = rem & 7;
        gload_lds16(base + (size_t)row * 16640 + xx * 128 + ((cs ^ (xx & 7)) << 4),
                    tile + n * 16);
    }
    if (t < 160) {
        int n = 2560 + t;
        int row = n / 272, rem = n - row * 272;
        int xx = rem >> 3, cs = rem & 7;
        gload_lds16(base + (size_t)row * 16640 + xx * 128 + ((cs ^ (xx & 7)) << 4),
                    tile + n * 16);
    }
}

__device__ __forceinline__ void conv3x3w2(f32x16 (&acc)[2][2], const unsigned short* __restrict__ Wt,
                                          const char* tile, int w, int lane) {
    int px = lane & 31, hi = lane >> 5;
    #pragma unroll
    for (int tap = 0; tap < 9; ++tap) {
        const int di = tap / 3, dj = tap % 3;
        short8 wa[2][4];
        #pragma unroll
        for (int Kq = 0; Kq < 4; ++Kq)
            #pragma unroll
            for (int oh = 0; oh < 2; ++oh)
                wa[oh][Kq] = *(const short8*)(Wt + ((((tap * 4 + Kq) * 2 + oh) * 64 + lane) << 3));
        const int xx = px + dj;
        #pragma unroll
        for (int pxg = 0; pxg < 2; ++pxg) {
            const char* base = tile + (w * 2 + pxg + di) * 4352 + xx * 128;
            #pragma unroll
            for (int Kq = 0; Kq < 4; ++Kq) {
                short8 bf = *(const short8*)(base + (((Kq * 2 + hi) ^ (xx & 7)) << 4));
                __builtin_amdgcn_s_setprio(1);
                acc[0][pxg] = __builtin_amdgcn_mfma_f32_32x32x16_bf16(wa[0][Kq], bf, acc[0][pxg], 0, 0, 0);
                acc[1][pxg] = __builtin_amdgcn_mfma_f32_32x32x16_bf16(wa[1][Kq], bf, acc[1][pxg], 0, 0, 0);
                __builtin_amdgcn_s_setprio(0);
            }
        }
    }
}

__global__ __launch_bounds__(256, 2) void k_fused(const unsigned short* __restrict__ rgbT,
                                                  const unsigned short* __restrict__ depthT,
                                                  const float* __restrict__ ws,
                                                  float* __restrict__ out) {
    __shared__ __align__(16) char tile[43520];
    int b = blockIdx.z;
    int x0 = blockIdx.x * 32, y0 = blockIdx.y * 8;
    int t = threadIdx.x, lane = t & 63, w = t >> 6;
    int px = lane & 31, hi = lane >> 5;

    const unsigned short* wfd = (const unsigned short*)((const char*)ws + WFD_BYTE);
    const unsigned short* wt3 = (const unsigned short*)((const char*)ws + WT3_BYTE);
    const unsigned short* w1o = (const unsigned short*)((const char*)ws + W1_BYTE);

    // ---- issue depth tile loads (async into LDS) ----
    stage_async(depthT, b, y0, x0, t, tile);

    // facc init = fd beta (C-layout: och = oh*32 + (r&3) + 8*(r>>2) + 4*hi)
    f32x16 facc[2][2];
    #pragma unroll
    for (int oh = 0; oh < 2; ++oh) {
        f32x16 bi;
        #pragma unroll
        for (int r = 0; r < 16; ++r)
            bi[r] = ws[WS_FDBETA + oh * 32 + (r & 3) + 8 * (r >> 2) + 4 * hi];
        facc[oh][0] = bi;
        facc[oh][1] = bi;
    }
    __syncthreads();   // depth tile resident

    conv3x3w2(facc, wfd, tile, w, lane);
    __syncthreads();   // depth-tile reads done; reuse tile[0..32768) as freq_lds

    // ---- freq -> LDS [px][ch] bf16, chunk-slot XOR by (px&7), ReLU ----
    {
        unsigned int* fl = (unsigned int*)tile;
        #pragma unroll
        for (int oh = 0; oh < 2; ++oh)
            #pragma unroll
            for (int pxg = 0; pxg < 2; ++pxg) {
                int p = (w * 2 + pxg) * 32 + px;
                #pragma unroll
                for (int q = 0; q < 4; ++q) {
                    unsigned int u0 = pack_bf16(fmaxf(facc[oh][pxg][q * 4 + 0], 0.f),
                                                fmaxf(facc[oh][pxg][q * 4 + 1], 0.f));
                    unsigned int u1 = pack_bf16(fmaxf(facc[oh][pxg][q * 4 + 2], 0.f),
                                                fmaxf(facc[oh][pxg][q * 4 + 3], 0.f));
                    int slot = (q + oh * 4) ^ (p & 7);
                    int dw = p * 32 + slot * 4 + hi * 2;
                    fl[dw] = u0;
                    fl[dw + 1] = u1;
                }
            }
    }
    __syncthreads();   // freq_lds visible

    // ---- acc init + 1x1 over freq ----
    f32x16 acc[2][2];
    #pragma unroll
    for (int oh = 0; oh < 2; ++oh) {
        f32x16 bi;
        #pragma unroll
        for (int r = 0; r < 16; ++r)
            bi[r] = ws[WS_FUBETA + oh * 32 + (r & 3) + 8 * (r >> 2) + 4 * hi];
        acc[oh][0] = bi;
        acc[oh][1] = bi;
    }
    #pragma unroll
    for (int Kq = 0; Kq < 4; ++Kq) {
        short8 w1a[2];
        #pragma unroll
        for (int oh = 0; oh < 2; ++oh)
            w1a[oh] = *(const short8*)(w1o + (((Kq * 2 + oh) * 64 + lane) << 3));
        #pragma unroll
        for (int pxg = 0; pxg < 2; ++pxg) {
            int p = (w * 2 + pxg) * 32 + px;
            short8 bf = *(const short8*)(tile + p * 128 + (((Kq * 2 + hi) ^ (p & 7)) << 4));
            __builtin_amdgcn_s_setprio(1);
            acc[0][pxg] = __builtin_amdgcn_mfma_f32_32x32x16_bf16(w1a[0], bf, acc[0][pxg], 0, 0, 0);
            acc[1][pxg] = __builtin_amdgcn_mfma_f32_32x32x16_bf16(w1a[1], bf, acc[1][pxg], 0, 0, 0);
            __builtin_amdgcn_s_setprio(0);
        }
    }
    __syncthreads();   // freq_lds reads done

    // ---- issue rgb tile loads ----
    stage_async(rgbT, b, y0, x0, t, tile);
    __syncthreads();   // rgb tile resident

    conv3x3w2(acc, wt3, tile, w, lane);
    __syncthreads();   // tile reads done; reuse as transpose slab

    // ---- epilogue: per-wave 64x33 slab transpose -> full-128B-line stores ----
    float* slab = (float*)(tile + w * 8704);
    #pragma unroll
    for (int pxg = 0; pxg < 2; ++pxg) {
        #pragma unroll
        for (int oh = 0; oh < 2; ++oh)
            #pragma unroll
            for (int q = 0; q < 4; ++q)
                #pragma unroll
                for (int i = 0; i < 4; ++i)
                    slab[(oh * 32 + q * 8 + hi * 4 + i) * 33 + px] =
                        fmaxf(acc[oh][pxg][q * 4 + i], 0.f);
        int y = y0 + w * 2 + pxg;
        #pragma unroll
        for (int c2 = 0; c2 < 32; ++c2) {
            int c = c2 * 2 + hi;
            out[(size_t)(b * CB + c) * HWSZ + (size_t)y * WW + x0 + px] = slab[c * 33 + px];
        }
    }
}

// ---------------- launch ----------------

extern "C" void kernel_launch(void* const* d_in, const int* in_sizes, int n_in,
                              void* d_out, int out_size, void* d_ws, size_t ws_size,
                              hipStream_t stream) {
    const float* rgb      = (const float*)d_in[0];
    const float* depth    = (const float*)d_in[1];
    const float* w1       = (const float*)d_in[2];
    const float* b1       = (const float*)d_in[3];
    const float* w2       = (const float*)d_in[4];
    const float* b2       = (const float*)d_in[5];
    const float* fd_w     = (const float*)d_in[6];
    const float* fd_b     = (const float*)d_in[7];
    const float* fd_scale = (const float*)d_in[8];
    const float* fd_bias  = (const float*)d_in[9];
    const float* fd_mean  = (const float*)d_in[10];
    const float* fd_var   = (const float*)d_in[11];
    const float* fu_w     = (const float*)d_in[12];
    const float* fu_b     = (const float*)d_in[13];
    const float* fu_scale = (const float*)d_in[14];
    const float* fu_bias  = (const float*)d_in[15];
    const float* fu_mean  = (const float*)d_in[16];
    const float* fu_var   = (const float*)d_in[17];

    float* ws = (float*)d_ws;
    float* part = (float*)((char*)d_ws + WS_PART_BYTE);
    unsigned int* depthT = (unsigned int*)((char*)d_ws + WS_DEPTHT_BYTE);
    unsigned int* rgbT   = (unsigned int*)((char*)d_ws + WS_RGBT_BYTE);
    float* out = (float*)d_out;

    k_consts<<<1, 64, 0, stream>>>(fd_scale, fd_bias, fd_mean, fd_var, fd_b,
                                   fu_scale, fu_bias, fu_mean, fu_var, fu_b, ws);
    k_nhwc<<<dim3(65, 64), 256, 0, stream>>>(rgb, depth, rgbT, depthT, part);
    k_pool2<<<CB, 256, 0, stream>>>(part, ws);
    k_hid<<<CB, 128, 0, stream>>>(w1, b1, ws);
    k_kern<<<CB, 256, 0, stream>>>(w2, b2, ws);
    k_wk<<<CB, 256, 0, stream>>>(ws);
    k_effw<<<CB, 256, 0, stream>>>(fu_w, ws);
    k_prepw<<<304, 256, 0, stream>>>(fd_w, ws);

    dim3 grid(WW / 32, HH / 8, CB);
    k_fused<<<grid, 256, 0, stream>>>((const unsigned short*)rgbT,
                                      (const unsigned short*)depthT, ws, out);
}